// Round 3
// baseline (476.150 us; speedup 1.0000x reference)
//
#include <hip/hip_runtime.h>
#include <hip/hip_bf16.h>
#include <stdint.h>

// ---------------------------------------------------------------------------
// Problem constants (match reference)
// ---------------------------------------------------------------------------
#define KA 22500            // anchors
#define NI 32               // images
#define MG 50               // gt boxes per image
#define NK (NI * KA)        // 720000 labels
#define HNK (NK / 2)        // 360000 (legacy threefry pairing)
#define COEFF_OFF NK        // f32 element offset of coeff block in d_out
#define IDX_OFF (NK * 5)    // f32 element offset of anchors_idx block (3,600,000)
#define MAXFG 128
#define TOTALA 256
#define NBUCK 4096
#define SELCAP 1024

// RNG mode: 1 = jax_threefry_partitionable (default since JAX 0.5.0).
#define THREEFRY_PARTITIONABLE 1

// ---------------------------------------------------------------------------
// Threefry-2x32 (matches jax._src.prng exactly)
// ---------------------------------------------------------------------------
__host__ __device__ __forceinline__ uint32_t rotl32(uint32_t v, int r) {
  return (v << r) | (v >> (32 - r));
}

__host__ __device__ __forceinline__ void threefry2x32(uint32_t k0, uint32_t k1,
                                                      uint32_t x0, uint32_t x1,
                                                      uint32_t& o0, uint32_t& o1) {
  uint32_t k2 = k0 ^ k1 ^ 0x1BD11BDAu;
  x0 += k0; x1 += k1;
  x0 += x1; x1 = rotl32(x1, 13); x1 ^= x0;
  x0 += x1; x1 = rotl32(x1, 15); x1 ^= x0;
  x0 += x1; x1 = rotl32(x1, 26); x1 ^= x0;
  x0 += x1; x1 = rotl32(x1, 6);  x1 ^= x0;
  x0 += k1; x1 += k2 + 1u;
  x0 += x1; x1 = rotl32(x1, 17); x1 ^= x0;
  x0 += x1; x1 = rotl32(x1, 29); x1 ^= x0;
  x0 += x1; x1 = rotl32(x1, 16); x1 ^= x0;
  x0 += x1; x1 = rotl32(x1, 24); x1 ^= x0;
  x0 += k2; x1 += k0 + 2u;
  x0 += x1; x1 = rotl32(x1, 13); x1 ^= x0;
  x0 += x1; x1 = rotl32(x1, 15); x1 ^= x0;
  x0 += x1; x1 = rotl32(x1, 26); x1 ^= x0;
  x0 += x1; x1 = rotl32(x1, 6);  x1 ^= x0;
  x0 += k0; x1 += k1 + 3u;
  x0 += x1; x1 = rotl32(x1, 17); x1 ^= x0;
  x0 += x1; x1 = rotl32(x1, 29); x1 ^= x0;
  x0 += x1; x1 = rotl32(x1, 16); x1 ^= x0;
  x0 += x1; x1 = rotl32(x1, 24); x1 ^= x0;
  x0 += k1; x1 += k2 + 4u;
  x0 += x1; x1 = rotl32(x1, 13); x1 ^= x0;
  x0 += x1; x1 = rotl32(x1, 15); x1 ^= x0;
  x0 += x1; x1 = rotl32(x1, 26); x1 ^= x0;
  x0 += x1; x1 = rotl32(x1, 6);  x1 ^= x0;
  x0 += k2; x1 += k0 + 5u;
  o0 = x0; o1 = x1;
}

// 23-bit uniform mantissa for flat index j under subkey (c0,c1).
__device__ __forceinline__ uint32_t rand_m23(uint32_t c0, uint32_t c1, uint32_t j) {
#if THREEFRY_PARTITIONABLE
  uint32_t o0, o1;
  threefry2x32(c0, c1, 0u, j, o0, o1);
  return (o0 ^ o1) >> 9;
#else
  uint32_t o0, o1;
  if (j < (uint32_t)HNK) {
    threefry2x32(c0, c1, j, j + (uint32_t)HNK, o0, o1);
    return o0 >> 9;
  }
  threefry2x32(c0, c1, j - (uint32_t)HNK, j, o0, o1);
  return o1 >> 9;
#endif
}

// ---------------------------------------------------------------------------
// Bit-exact IoU (no FMA contraction: equality/argmax vs numpy f32 sequence)
// ---------------------------------------------------------------------------
__device__ __forceinline__ float areaf(float x1, float y1, float x2, float y2) {
#pragma clang fp contract(off)
  return ((x2 - x1) + 1.0f) * ((y2 - y1) + 1.0f);
}

__device__ __forceinline__ float iou_f(float a0, float a1, float a2, float a3,
                                       float areaA, float g0, float g1, float g2,
                                       float g3, float areaG) {
#pragma clang fp contract(off)
  float ix1 = fmaxf(a0, g0);
  float iy1 = fmaxf(a1, g1);
  float ix2 = fminf(a2, g2);
  float iy2 = fminf(a3, g3);
  float iw = fmaxf((ix2 - ix1) + 1.0f, 0.0f);
  float ih = fmaxf((iy2 - iy1) + 1.0f, 0.0f);
  float inter = iw * ih;
  return inter / ((areaA + areaG) - inter);
}

// ---------------------------------------------------------------------------
// K0: zero colmax
// ---------------------------------------------------------------------------
__global__ __launch_bounds__(256) void k0_init(uint32_t* __restrict__ colmax) {
  int i = blockIdx.x * 256 + threadIdx.x;
  if (i < NI * MG) colmax[i] = 0u;
}

// ---------------------------------------------------------------------------
// K1: colmax[n][m] = max_k IoU(anchor k, gt (n,m)).
// ---------------------------------------------------------------------------
__global__ __launch_bounds__(256) void k1_colmax(const float4* __restrict__ a4,
                                                 const float* __restrict__ gt,
                                                 uint32_t* __restrict__ colmax) {
  int n = blockIdx.y;
  int tid = threadIdx.x;
  __shared__ float gs[MG * 4];
  __shared__ float gAs[MG];
  __shared__ uint32_t lmax[MG];
  if (tid < MG * 4) gs[tid] = gt[n * MG * 4 + tid];
  if (tid < MG) lmax[tid] = 0u;
  __syncthreads();
  if (tid < MG)
    gAs[tid] = areaf(gs[4 * tid], gs[4 * tid + 1], gs[4 * tid + 2], gs[4 * tid + 3]);
  __syncthreads();

  float best[MG];
#pragma unroll
  for (int m = 0; m < MG; ++m) best[m] = 0.0f;

  int per = (KA + gridDim.x - 1) / gridDim.x;
  int kbeg = blockIdx.x * per;
  int kend = kbeg + per;
  if (kend > KA) kend = KA;
  for (int k = kbeg + tid; k < kend; k += 256) {
    float4 a = a4[k];
    float areaA = areaf(a.x, a.y, a.z, a.w);
#pragma unroll
    for (int m = 0; m < MG; ++m) {
      float v = iou_f(a.x, a.y, a.z, a.w, areaA,
                      gs[4 * m], gs[4 * m + 1], gs[4 * m + 2], gs[4 * m + 3], gAs[m]);
      best[m] = fmaxf(best[m], v);
    }
  }
#pragma unroll
  for (int m = 0; m < MG; ++m) {
    float b = best[m];
    b = fmaxf(b, __shfl_down(b, 32));
    b = fmaxf(b, __shfl_down(b, 16));
    b = fmaxf(b, __shfl_down(b, 8));
    b = fmaxf(b, __shfl_down(b, 4));
    b = fmaxf(b, __shfl_down(b, 2));
    b = fmaxf(b, __shfl_down(b, 1));
    if ((tid & 63) == 0) atomicMax(&lmax[m], __float_as_uint(b));
  }
  __syncthreads();
  if (tid < MG) atomicMax(&colmax[n * MG + tid], lmax[tid]);
}

// ---------------------------------------------------------------------------
// K2: per-(n,k): flags, argmax gt, provisional f32 labels, f32 coeffs.
// ---------------------------------------------------------------------------
__global__ __launch_bounds__(256) void k2_main(const float4* __restrict__ a4,
                                               const float* __restrict__ gt,
                                               const uint32_t* __restrict__ colmax,
                                               float* __restrict__ out_lbl,
                                               float4* __restrict__ out_coeff) {
  int n = blockIdx.y;
  int tid = threadIdx.x;
  __shared__ float gs[MG * 4];
  __shared__ float gAs[MG];
  __shared__ uint32_t cms[MG];
  if (tid < MG * 4) gs[tid] = gt[n * MG * 4 + tid];
  __syncthreads();
  if (tid < MG) {
    gAs[tid] = areaf(gs[4 * tid], gs[4 * tid + 1], gs[4 * tid + 2], gs[4 * tid + 3]);
    cms[tid] = colmax[n * MG + tid];
  }
  __syncthreads();

  int k = blockIdx.x * 256 + tid;
  if (k >= KA) return;
  float4 a = a4[k];
  float areaA = areaf(a.x, a.y, a.z, a.w);

  float best = -1.0f;
  int bi = 0;
  bool anyp = false, anyn = false, abox = false;
#pragma unroll 5
  for (int m = 0; m < MG; ++m) {
    float v = iou_f(a.x, a.y, a.z, a.w, areaA,
                    gs[4 * m], gs[4 * m + 1], gs[4 * m + 2], gs[4 * m + 3], gAs[m]);
    if (v > best) { best = v; bi = m; }   // first-index argmax like np.argmax
    anyp = anyp || (v >= 0.7f);
    anyn = anyn || (v >= 0.3f);
    abox = abox || (__float_as_uint(v) == cms[m]);  // exact equality vs column max
  }
  out_lbl[n * KA + k] = (abox || anyp) ? 1.0f : (anyn ? -1.0f : 0.0f);

  // regression coefficients to argmax gt box (own block so the pragma is legal)
  {
#pragma clang fp contract(off)
    float g0 = gs[4 * bi], g1 = gs[4 * bi + 1], g2 = gs[4 * bi + 2], g3 = gs[4 * bi + 3];
    float aw = a.z - a.x + 1.0f, ah = a.w - a.y + 1.0f;
    float ax = a.x + 0.5f * aw, ay = a.y + 0.5f * ah;
    float gw = g2 - g0 + 1.0f, gh = g3 - g1 + 1.0f;
    float gx = g0 + 0.5f * gw, gy = g1 + 0.5f * gh;
    float4 c;
    c.x = (gx - ax) / aw;
    c.y = (gy - ay) / ah;
    c.z = logf(gw / aw);
    c.w = logf(gh / ah);
    out_coeff[n * KA + k] = c;
  }
}

// ---------------------------------------------------------------------------
// K3: per-row exact T-th order statistic of (uniform,index) among fg / bg.
// theta = T-th smallest (m23,k) key; keep iff key <= theta.
// ---------------------------------------------------------------------------
__global__ __launch_bounds__(256) void k3_select(const float* __restrict__ lbl,
                                                 uint64_t* __restrict__ theta_fg,
                                                 uint64_t* __restrict__ theta_bg,
                                                 uint32_t k10, uint32_t k11,
                                                 uint32_t k20, uint32_t k21) {
  __shared__ uint32_t hist[NBUCK];
  __shared__ uint32_t colm[SELCAP];
  __shared__ uint32_t colk[SELCAP];
  __shared__ uint32_t ccnt;
  __shared__ int sB;
  __shared__ uint32_t sR;
  __shared__ uint32_t s_numfg;

  int n = blockIdx.x;
  int tid = threadIdx.x;
  const float* lb = lbl + n * KA;

  for (int phase = 0; phase < 2; ++phase) {
    float match = phase ? 0.0f : 1.0f;
    uint32_t c0 = phase ? k20 : k10;
    uint32_t c1 = phase ? k21 : k11;
    for (int i = tid; i < NBUCK; i += 256) hist[i] = 0u;
    if (tid == 0) { ccnt = 0u; sB = -1; }
    __syncthreads();

    for (int k = tid; k < KA; k += 256)
      if (lb[k] == match)
        atomicAdd(&hist[rand_m23(c0, c1, (uint32_t)(n * KA + k)) >> 11], 1u);
    __syncthreads();

    if (tid == 0) {
      uint32_t total = 0;
      for (int i = 0; i < NBUCK; ++i) total += hist[i];
      if (phase == 0) s_numfg = total < (uint32_t)MAXFG ? total : (uint32_t)MAXFG;
      uint32_t T = phase == 0 ? (uint32_t)MAXFG : (uint32_t)TOTALA - s_numfg;
      if (total > T) {
        uint32_t cum = 0;
        for (int i = 0; i < NBUCK; ++i) {
          if (cum + hist[i] >= T) { sB = i; sR = T - cum; break; }
          cum += hist[i];
        }
      }
    }
    __syncthreads();

    if (sB >= 0) {
      for (int k = tid; k < KA; k += 256) {
        if (lb[k] == match) {
          uint32_t m = rand_m23(c0, c1, (uint32_t)(n * KA + k));
          if ((int)(m >> 11) == sB) {
            uint32_t i = atomicAdd(&ccnt, 1u);
            if (i < SELCAP) { colm[i] = m; colk[i] = (uint32_t)k; }
          }
        }
      }
      __syncthreads();
      if (tid == 0) {
        uint32_t C = ccnt < (uint32_t)SELCAP ? ccnt : (uint32_t)SELCAP;
        uint64_t prev = 0ull;
        for (uint32_t r = 0; r < sR; ++r) {  // sR-th smallest via successive minima
          uint64_t bst = ~0ull;
          for (uint32_t c = 0; c < C; ++c) {
            uint64_t key = ((uint64_t)colm[c] << 32) | (uint64_t)colk[c];
            if ((r == 0 || key > prev) && key < bst) bst = key;
          }
          prev = bst;
        }
        (phase ? theta_bg : theta_fg)[n] = prev;
      }
    } else {
      if (tid == 0) (phase ? theta_bg : theta_fg)[n] = ~0ull;  // keep all
    }
    __syncthreads();
  }
}

// ---------------------------------------------------------------------------
// K4: final labels (drop fg/bg beyond threshold) + anchors_idx (f32)
// ---------------------------------------------------------------------------
__global__ __launch_bounds__(256) void k4_final(float* __restrict__ lbl,
                                                float* __restrict__ out_idx,
                                                const uint64_t* __restrict__ theta_fg,
                                                const uint64_t* __restrict__ theta_bg,
                                                uint32_t k10, uint32_t k11,
                                                uint32_t k20, uint32_t k21) {
  int n = blockIdx.y;
  int k = blockIdx.x * 256 + threadIdx.x;
  if (k >= KA) return;
  float v = lbl[n * KA + k];
  if (v == 1.0f) {
    uint64_t key = ((uint64_t)rand_m23(k10, k11, (uint32_t)(n * KA + k)) << 32) | (uint32_t)k;
    if (key > theta_fg[n]) lbl[n * KA + k] = -1.0f;
  } else if (v == 0.0f) {
    uint64_t key = ((uint64_t)rand_m23(k20, k21, (uint32_t)(n * KA + k)) << 32) | (uint32_t)k;
    if (key > theta_bg[n]) lbl[n * KA + k] = -1.0f;
  }
  if (n == 0) out_idx[k] = (float)k;  // all anchors kept by construction
}

// ---------------------------------------------------------------------------
// Launch
// ---------------------------------------------------------------------------
extern "C" void kernel_launch(void* const* d_in, const int* in_sizes, int n_in,
                              void* d_out, int out_size, void* d_ws, size_t ws_size,
                              hipStream_t stream) {
  const float* anchors = (const float*)d_in[0];   // [22500,4] f32
  const float* gt = (const float*)d_in[1];        // [32,50,4] f32
  float* out_f = (float*)d_out;                   // f32 buffer, 3,622,500 elems
  float* out_lbl = out_f;                         // [32,22500]
  float4* out_coeff = (float4*)(out_f + COEFF_OFF);  // [32,22500,4], 16B-aligned
  float* out_idx = out_f + IDX_OFF;               // [22500]

  // ws layout: colmax [0,6400) | theta_fg @6528 (32*8B) | theta_bg @6784
  uint32_t* colmax = (uint32_t*)d_ws;
  uint64_t* theta_fg = (uint64_t*)((char*)d_ws + 6528);
  uint64_t* theta_bg = (uint64_t*)((char*)d_ws + 6784);

  // subkeys of jax.random.split(jax.random.key(42)), derived host-side
  uint32_t k10, k11, k20, k21;
#if THREEFRY_PARTITIONABLE
  threefry2x32(0u, 42u, 0u, 0u, k10, k11);
  threefry2x32(0u, 42u, 0u, 1u, k20, k21);
#else
  uint32_t a0, a1, b0, b1;
  threefry2x32(0u, 42u, 0u, 2u, a0, a1);
  threefry2x32(0u, 42u, 1u, 3u, b0, b1);
  k10 = a0; k11 = b0;
  k20 = a1; k21 = b1;
#endif

  const int KBLK = (KA + 255) / 256;  // 88
  k0_init<<<7, 256, 0, stream>>>(colmax);
  k1_colmax<<<dim3(16, NI), 256, 0, stream>>>((const float4*)anchors, gt, colmax);
  k2_main<<<dim3(KBLK, NI), 256, 0, stream>>>((const float4*)anchors, gt, colmax,
                                              out_lbl, out_coeff);
  k3_select<<<NI, 256, 0, stream>>>(out_lbl, theta_fg, theta_bg, k10, k11, k20, k21);
  k4_final<<<dim3(KBLK, NI), 256, 0, stream>>>(out_lbl, out_idx, theta_fg, theta_bg,
                                               k10, k11, k20, k21);
}

// Round 4
// 176.337 us; speedup vs baseline: 2.7002x; 2.7002x over previous
//
#include <hip/hip_runtime.h>
#include <hip/hip_bf16.h>
#include <stdint.h>

// ---------------------------------------------------------------------------
// Problem constants (match reference)
// ---------------------------------------------------------------------------
#define KA 22500            // anchors
#define NI 32               // images
#define MG 50               // gt boxes per image
#define NK (NI * KA)        // 720000 labels
#define HNK (NK / 2)        // 360000 (legacy threefry pairing)
#define COEFF_OFF NK        // f32 element offset of coeff block in d_out
#define IDX_OFF (NK * 5)    // f32 element offset of anchors_idx block (3,600,000)
#define MAXFG 128
#define TOTALA 256
#define NBUCK 4096
#define SELCAP 1024

// RNG mode: 1 = jax_threefry_partitionable (default since JAX 0.5.0).
#define THREEFRY_PARTITIONABLE 1

// ---------------------------------------------------------------------------
// Threefry-2x32 (matches jax._src.prng exactly)
// ---------------------------------------------------------------------------
__host__ __device__ __forceinline__ uint32_t rotl32(uint32_t v, int r) {
  return (v << r) | (v >> (32 - r));
}

__host__ __device__ __forceinline__ void threefry2x32(uint32_t k0, uint32_t k1,
                                                      uint32_t x0, uint32_t x1,
                                                      uint32_t& o0, uint32_t& o1) {
  uint32_t k2 = k0 ^ k1 ^ 0x1BD11BDAu;
  x0 += k0; x1 += k1;
  x0 += x1; x1 = rotl32(x1, 13); x1 ^= x0;
  x0 += x1; x1 = rotl32(x1, 15); x1 ^= x0;
  x0 += x1; x1 = rotl32(x1, 26); x1 ^= x0;
  x0 += x1; x1 = rotl32(x1, 6);  x1 ^= x0;
  x0 += k1; x1 += k2 + 1u;
  x0 += x1; x1 = rotl32(x1, 17); x1 ^= x0;
  x0 += x1; x1 = rotl32(x1, 29); x1 ^= x0;
  x0 += x1; x1 = rotl32(x1, 16); x1 ^= x0;
  x0 += x1; x1 = rotl32(x1, 24); x1 ^= x0;
  x0 += k2; x1 += k0 + 2u;
  x0 += x1; x1 = rotl32(x1, 13); x1 ^= x0;
  x0 += x1; x1 = rotl32(x1, 15); x1 ^= x0;
  x0 += x1; x1 = rotl32(x1, 26); x1 ^= x0;
  x0 += x1; x1 = rotl32(x1, 6);  x1 ^= x0;
  x0 += k0; x1 += k1 + 3u;
  x0 += x1; x1 = rotl32(x1, 17); x1 ^= x0;
  x0 += x1; x1 = rotl32(x1, 29); x1 ^= x0;
  x0 += x1; x1 = rotl32(x1, 16); x1 ^= x0;
  x0 += x1; x1 = rotl32(x1, 24); x1 ^= x0;
  x0 += k1; x1 += k2 + 4u;
  x0 += x1; x1 = rotl32(x1, 13); x1 ^= x0;
  x0 += x1; x1 = rotl32(x1, 15); x1 ^= x0;
  x0 += x1; x1 = rotl32(x1, 26); x1 ^= x0;
  x0 += x1; x1 = rotl32(x1, 6);  x1 ^= x0;
  x0 += k2; x1 += k0 + 5u;
  o0 = x0; o1 = x1;
}

// 23-bit uniform mantissa for flat index j under subkey (c0,c1).
__device__ __forceinline__ uint32_t rand_m23(uint32_t c0, uint32_t c1, uint32_t j) {
#if THREEFRY_PARTITIONABLE
  uint32_t o0, o1;
  threefry2x32(c0, c1, 0u, j, o0, o1);
  return (o0 ^ o1) >> 9;
#else
  uint32_t o0, o1;
  if (j < (uint32_t)HNK) {
    threefry2x32(c0, c1, j, j + (uint32_t)HNK, o0, o1);
    return o0 >> 9;
  }
  threefry2x32(c0, c1, j - (uint32_t)HNK, j, o0, o1);
  return o1 >> 9;
#endif
}

// ---------------------------------------------------------------------------
// Bit-exact IoU (no FMA contraction: equality/argmax vs numpy f32 sequence)
// ---------------------------------------------------------------------------
__device__ __forceinline__ float areaf(float x1, float y1, float x2, float y2) {
#pragma clang fp contract(off)
  return ((x2 - x1) + 1.0f) * ((y2 - y1) + 1.0f);
}

__device__ __forceinline__ float iou_f(float a0, float a1, float a2, float a3,
                                       float areaA, float g0, float g1, float g2,
                                       float g3, float areaG) {
#pragma clang fp contract(off)
  float ix1 = fmaxf(a0, g0);
  float iy1 = fmaxf(a1, g1);
  float ix2 = fminf(a2, g2);
  float iy2 = fminf(a3, g3);
  float iw = fmaxf((ix2 - ix1) + 1.0f, 0.0f);
  float ih = fmaxf((iy2 - iy1) + 1.0f, 0.0f);
  float inter = iw * ih;
  return inter / ((areaA + areaG) - inter);
}

// ---------------------------------------------------------------------------
// K0: zero colmax (1600 u32) + fgcnt (32 u32), contiguous at ws[0..1632)
// ---------------------------------------------------------------------------
__global__ __launch_bounds__(256) void k0_init(uint32_t* __restrict__ ws32) {
  int i = blockIdx.x * 256 + threadIdx.x;
  if (i < NI * MG + NI) ws32[i] = 0u;
}

// ---------------------------------------------------------------------------
// K1: colmax[n][m] = max_k IoU(anchor k, gt (n,m)).
// ---------------------------------------------------------------------------
__global__ __launch_bounds__(256) void k1_colmax(const float4* __restrict__ a4,
                                                 const float* __restrict__ gt,
                                                 uint32_t* __restrict__ colmax) {
  int n = blockIdx.y;
  int tid = threadIdx.x;
  __shared__ float gs[MG * 4];
  __shared__ float gAs[MG];
  __shared__ uint32_t lmax[MG];
  if (tid < MG * 4) gs[tid] = gt[n * MG * 4 + tid];
  if (tid < MG) lmax[tid] = 0u;
  __syncthreads();
  if (tid < MG)
    gAs[tid] = areaf(gs[4 * tid], gs[4 * tid + 1], gs[4 * tid + 2], gs[4 * tid + 3]);
  __syncthreads();

  float best[MG];
#pragma unroll
  for (int m = 0; m < MG; ++m) best[m] = 0.0f;

  int per = (KA + gridDim.x - 1) / gridDim.x;
  int kbeg = blockIdx.x * per;
  int kend = kbeg + per;
  if (kend > KA) kend = KA;
  for (int k = kbeg + tid; k < kend; k += 256) {
    float4 a = a4[k];
    float areaA = areaf(a.x, a.y, a.z, a.w);
#pragma unroll
    for (int m = 0; m < MG; ++m) {
      float v = iou_f(a.x, a.y, a.z, a.w, areaA,
                      gs[4 * m], gs[4 * m + 1], gs[4 * m + 2], gs[4 * m + 3], gAs[m]);
      best[m] = fmaxf(best[m], v);
    }
  }
#pragma unroll
  for (int m = 0; m < MG; ++m) {
    float b = best[m];
    b = fmaxf(b, __shfl_down(b, 32));
    b = fmaxf(b, __shfl_down(b, 16));
    b = fmaxf(b, __shfl_down(b, 8));
    b = fmaxf(b, __shfl_down(b, 4));
    b = fmaxf(b, __shfl_down(b, 2));
    b = fmaxf(b, __shfl_down(b, 1));
    if ((tid & 63) == 0) atomicMax(&lmax[m], __float_as_uint(b));
  }
  __syncthreads();
  if (tid < MG) atomicMax(&colmax[n * MG + tid], lmax[tid]);
}

// ---------------------------------------------------------------------------
// K2: per-(n,k): flags, argmax gt, provisional f32 labels, f32 coeffs,
//     and per-row fg count (enables fg/bg phase parallelism in K3).
// ---------------------------------------------------------------------------
__global__ __launch_bounds__(256) void k2_main(const float4* __restrict__ a4,
                                               const float* __restrict__ gt,
                                               const uint32_t* __restrict__ colmax,
                                               float* __restrict__ out_lbl,
                                               float4* __restrict__ out_coeff,
                                               uint32_t* __restrict__ fgcnt) {
  int n = blockIdx.y;
  int tid = threadIdx.x;
  __shared__ float gs[MG * 4];
  __shared__ float gAs[MG];
  __shared__ uint32_t cms[MG];
  if (tid < MG * 4) gs[tid] = gt[n * MG * 4 + tid];
  __syncthreads();
  if (tid < MG) {
    gAs[tid] = areaf(gs[4 * tid], gs[4 * tid + 1], gs[4 * tid + 2], gs[4 * tid + 3]);
    cms[tid] = colmax[n * MG + tid];
  }
  __syncthreads();

  int k = blockIdx.x * 256 + tid;
  if (k >= KA) return;
  float4 a = a4[k];
  float areaA = areaf(a.x, a.y, a.z, a.w);

  float best = -1.0f;
  int bi = 0;
  bool anyp = false, anyn = false, abox = false;
#pragma unroll 5
  for (int m = 0; m < MG; ++m) {
    float v = iou_f(a.x, a.y, a.z, a.w, areaA,
                    gs[4 * m], gs[4 * m + 1], gs[4 * m + 2], gs[4 * m + 3], gAs[m]);
    if (v > best) { best = v; bi = m; }   // first-index argmax like np.argmax
    anyp = anyp || (v >= 0.7f);
    anyn = anyn || (v >= 0.3f);
    abox = abox || (__float_as_uint(v) == cms[m]);  // exact equality vs column max
  }
  bool is_fg = abox || anyp;
  out_lbl[n * KA + k] = is_fg ? 1.0f : (anyn ? -1.0f : 0.0f);
  if (is_fg) atomicAdd(&fgcnt[n], 1u);

  // regression coefficients to argmax gt box (own block so the pragma is legal)
  {
#pragma clang fp contract(off)
    float g0 = gs[4 * bi], g1 = gs[4 * bi + 1], g2 = gs[4 * bi + 2], g3 = gs[4 * bi + 3];
    float aw = a.z - a.x + 1.0f, ah = a.w - a.y + 1.0f;
    float ax = a.x + 0.5f * aw, ay = a.y + 0.5f * ah;
    float gw = g2 - g0 + 1.0f, gh = g3 - g1 + 1.0f;
    float gx = g0 + 0.5f * gw, gy = g1 + 0.5f * gh;
    float4 c;
    c.x = (gx - ax) / aw;
    c.y = (gy - ay) / ah;
    c.z = logf(gw / aw);
    c.w = logf(gh / ah);
    out_coeff[n * KA + k] = c;
  }
}

// ---------------------------------------------------------------------------
// K3: fully parallel T-th order statistic per (row, phase).
// Grid (NI, 2): blockIdx.y = 0 -> fg (T=128), 1 -> bg (T=256-min(fg,128)).
// theta = T-th smallest (m23,k) key among matching anchors; keep iff <= theta.
// Steps (all block-parallel, no single-lane scans):
//   1. histogram of m23>>11 into 4096 LDS buckets; m23 cached in LDS (90 KB)
//   2. 16-bucket chunk sums -> wave shfl_up scan -> block scan -> total +
//      crossing bucket sB and within-bucket rank sR
//   3. collect crossing-bucket candidates from the m23 cache
//   4. parallel rank-select: candidate with exactly sR-1 smaller keys
// ---------------------------------------------------------------------------
__global__ __launch_bounds__(256) void k3_select(const float* __restrict__ lbl,
                                                 const uint32_t* __restrict__ fgcnt,
                                                 uint64_t* __restrict__ theta_fg,
                                                 uint64_t* __restrict__ theta_bg,
                                                 uint32_t k10, uint32_t k11,
                                                 uint32_t k20, uint32_t k21) {
  __shared__ uint32_t hist[NBUCK];     // 16 KB
  __shared__ uint32_t mcache[KA];      // 90 KB (sentinel 0xFFFFFFFF = non-match)
  __shared__ uint32_t colm[SELCAP];
  __shared__ uint32_t colk[SELCAP];
  __shared__ uint32_t wtot[4];
  __shared__ uint32_t ccnt;
  __shared__ int sB;
  __shared__ uint32_t sR;

  int n = blockIdx.x;
  int phase = blockIdx.y;
  int tid = threadIdx.x;
  int lane = tid & 63;
  int wv = tid >> 6;
  const float* lb = lbl + n * KA;

  float match = phase ? 0.0f : 1.0f;
  uint32_t c0 = phase ? k20 : k10;
  uint32_t c1 = phase ? k21 : k11;
  uint64_t* theta = phase ? theta_bg : theta_fg;

  for (int i = tid; i < NBUCK; i += 256) hist[i] = 0u;
  if (tid == 0) { ccnt = 0u; sB = -1; }
  __syncthreads();

  // 1. histogram + m23 cache
  for (int k = tid; k < KA; k += 256) {
    uint32_t m = 0xFFFFFFFFu;
    if (lb[k] == match) {
      m = rand_m23(c0, c1, (uint32_t)(n * KA + k));
      atomicAdd(&hist[m >> 11], 1u);
    }
    mcache[k] = m;
  }
  __syncthreads();

  // 2. block scan over 16-bucket chunks
  const int CPB = NBUCK / 256;  // 16 buckets per thread
  int base = tid * CPB;
  uint32_t csum = 0;
#pragma unroll
  for (int i = 0; i < CPB; ++i) csum += hist[base + i];
  uint32_t x = csum;
#pragma unroll
  for (int d = 1; d < 64; d <<= 1) {
    uint32_t y = __shfl_up(x, d, 64);
    if (lane >= d) x += y;
  }
  if (lane == 63) wtot[wv] = x;
  __syncthreads();
  uint32_t woff = 0;
  for (int w = 0; w < wv; ++w) woff += wtot[w];
  uint32_t incl = x + woff;            // inclusive prefix over chunk sums
  uint32_t excl = incl - csum;
  uint32_t total = wtot[0] + wtot[1] + wtot[2] + wtot[3];

  uint32_t nf = fgcnt[n];
  uint32_t numfg = nf < (uint32_t)MAXFG ? nf : (uint32_t)MAXFG;
  uint32_t T = phase == 0 ? (uint32_t)MAXFG : (uint32_t)TOTALA - numfg;

  if (total <= T) {
    if (tid == 0) theta[n] = ~0ull;    // keep all matching
    return;
  }

  // crossing chunk: unique thread with excl < T <= incl
  if (excl < T && T <= incl) {
    uint32_t cum = excl;
    for (int i = 0; i < CPB; ++i) {
      uint32_t h = hist[base + i];
      if (cum + h >= T) { sB = base + i; sR = T - cum; break; }
      cum += h;
    }
  }
  __syncthreads();

  // 3. collect candidates in the crossing bucket (from cache; no threefry)
  int b = sB;
  for (int k = tid; k < KA; k += 256) {
    uint32_t m = mcache[k];
    if ((int)(m >> 11) == b) {
      uint32_t i = atomicAdd(&ccnt, 1u);
      if (i < SELCAP) { colm[i] = m; colk[i] = (uint32_t)k; }
    }
  }
  __syncthreads();

  // 4. parallel rank selection: the sR-th smallest key (keys distinct)
  uint32_t C = ccnt < (uint32_t)SELCAP ? ccnt : (uint32_t)SELCAP;
  uint32_t r = sR;
  for (uint32_t c = tid; c < C; c += 256) {
    uint64_t key = ((uint64_t)colm[c] << 32) | (uint64_t)colk[c];
    uint32_t less = 0;
    for (uint32_t j = 0; j < C; ++j) {
      uint64_t kj = ((uint64_t)colm[j] << 32) | (uint64_t)colk[j];
      less += (kj < key) ? 1u : 0u;
    }
    if (less == r - 1u) theta[n] = key;
  }
}

// ---------------------------------------------------------------------------
// K4: final labels (drop fg/bg beyond threshold) + anchors_idx (f32)
// ---------------------------------------------------------------------------
__global__ __launch_bounds__(256) void k4_final(float* __restrict__ lbl,
                                                float* __restrict__ out_idx,
                                                const uint64_t* __restrict__ theta_fg,
                                                const uint64_t* __restrict__ theta_bg,
                                                uint32_t k10, uint32_t k11,
                                                uint32_t k20, uint32_t k21) {
  int n = blockIdx.y;
  int k = blockIdx.x * 256 + threadIdx.x;
  if (k >= KA) return;
  float v = lbl[n * KA + k];
  if (v == 1.0f) {
    uint64_t key = ((uint64_t)rand_m23(k10, k11, (uint32_t)(n * KA + k)) << 32) | (uint32_t)k;
    if (key > theta_fg[n]) lbl[n * KA + k] = -1.0f;
  } else if (v == 0.0f) {
    uint64_t key = ((uint64_t)rand_m23(k20, k21, (uint32_t)(n * KA + k)) << 32) | (uint32_t)k;
    if (key > theta_bg[n]) lbl[n * KA + k] = -1.0f;
  }
  if (n == 0) out_idx[k] = (float)k;  // all anchors kept by construction
}

// ---------------------------------------------------------------------------
// Launch
// ---------------------------------------------------------------------------
extern "C" void kernel_launch(void* const* d_in, const int* in_sizes, int n_in,
                              void* d_out, int out_size, void* d_ws, size_t ws_size,
                              hipStream_t stream) {
  const float* anchors = (const float*)d_in[0];   // [22500,4] f32
  const float* gt = (const float*)d_in[1];        // [32,50,4] f32
  float* out_f = (float*)d_out;                   // f32 buffer, 3,622,500 elems
  float* out_lbl = out_f;                         // [32,22500]
  float4* out_coeff = (float4*)(out_f + COEFF_OFF);  // [32,22500,4], 16B-aligned
  float* out_idx = out_f + IDX_OFF;               // [22500]

  // ws layout (u32): colmax [0,1600) | fgcnt [1600,1632) | theta_fg @byte 6528 | theta_bg @6784
  uint32_t* ws32 = (uint32_t*)d_ws;
  uint32_t* colmax = ws32;
  uint32_t* fgcnt = ws32 + NI * MG;
  uint64_t* theta_fg = (uint64_t*)((char*)d_ws + 6528);
  uint64_t* theta_bg = (uint64_t*)((char*)d_ws + 6784);

  // subkeys of jax.random.split(jax.random.key(42)), derived host-side
  uint32_t k10, k11, k20, k21;
#if THREEFRY_PARTITIONABLE
  threefry2x32(0u, 42u, 0u, 0u, k10, k11);
  threefry2x32(0u, 42u, 0u, 1u, k20, k21);
#else
  uint32_t a0, a1, b0, b1;
  threefry2x32(0u, 42u, 0u, 2u, a0, a1);
  threefry2x32(0u, 42u, 1u, 3u, b0, b1);
  k10 = a0; k11 = b0;
  k20 = a1; k21 = b1;
#endif

  const int KBLK = (KA + 255) / 256;  // 88
  k0_init<<<7, 256, 0, stream>>>(ws32);
  k1_colmax<<<dim3(16, NI), 256, 0, stream>>>((const float4*)anchors, gt, colmax);
  k2_main<<<dim3(KBLK, NI), 256, 0, stream>>>((const float4*)anchors, gt, colmax,
                                              out_lbl, out_coeff, fgcnt);
  k3_select<<<dim3(NI, 2), 256, 0, stream>>>(out_lbl, fgcnt, theta_fg, theta_bg,
                                             k10, k11, k20, k21);
  k4_final<<<dim3(KBLK, NI), 256, 0, stream>>>(out_lbl, out_idx, theta_fg, theta_bg,
                                               k10, k11, k20, k21);
}

// Round 5
// 156.882 us; speedup vs baseline: 3.0351x; 1.1240x over previous
//
#include <hip/hip_runtime.h>
#include <hip/hip_bf16.h>
#include <stdint.h>

// ---------------------------------------------------------------------------
// Problem constants (match reference)
// ---------------------------------------------------------------------------
#define KA 22500            // anchors
#define NI 32               // images
#define MG 50               // gt boxes per image
#define NK (NI * KA)        // 720000 labels
#define HNK (NK / 2)        // 360000 (legacy threefry pairing)
#define COEFF_OFF NK        // f32 element offset of coeff block in d_out
#define IDX_OFF (NK * 5)    // f32 element offset of anchors_idx block (3,600,000)
#define MAXFG 128
#define TOTALA 256
#define NBUCK 4096
#define SELCAP 1024
#define MCHUNK 10           // gt boxes per k1 block (MG/MCHUNK chunks)
#define KC 16               // anchor chunks in k1 grid

// RNG mode: 1 = jax_threefry_partitionable (default since JAX 0.5.0).
#define THREEFRY_PARTITIONABLE 1

// ---------------------------------------------------------------------------
// Threefry-2x32 (matches jax._src.prng exactly)
// ---------------------------------------------------------------------------
__host__ __device__ __forceinline__ uint32_t rotl32(uint32_t v, int r) {
  return (v << r) | (v >> (32 - r));
}

__host__ __device__ __forceinline__ void threefry2x32(uint32_t k0, uint32_t k1,
                                                      uint32_t x0, uint32_t x1,
                                                      uint32_t& o0, uint32_t& o1) {
  uint32_t k2 = k0 ^ k1 ^ 0x1BD11BDAu;
  x0 += k0; x1 += k1;
  x0 += x1; x1 = rotl32(x1, 13); x1 ^= x0;
  x0 += x1; x1 = rotl32(x1, 15); x1 ^= x0;
  x0 += x1; x1 = rotl32(x1, 26); x1 ^= x0;
  x0 += x1; x1 = rotl32(x1, 6);  x1 ^= x0;
  x0 += k1; x1 += k2 + 1u;
  x0 += x1; x1 = rotl32(x1, 17); x1 ^= x0;
  x0 += x1; x1 = rotl32(x1, 29); x1 ^= x0;
  x0 += x1; x1 = rotl32(x1, 16); x1 ^= x0;
  x0 += x1; x1 = rotl32(x1, 24); x1 ^= x0;
  x0 += k2; x1 += k0 + 2u;
  x0 += x1; x1 = rotl32(x1, 13); x1 ^= x0;
  x0 += x1; x1 = rotl32(x1, 15); x1 ^= x0;
  x0 += x1; x1 = rotl32(x1, 26); x1 ^= x0;
  x0 += x1; x1 = rotl32(x1, 6);  x1 ^= x0;
  x0 += k0; x1 += k1 + 3u;
  x0 += x1; x1 = rotl32(x1, 17); x1 ^= x0;
  x0 += x1; x1 = rotl32(x1, 29); x1 ^= x0;
  x0 += x1; x1 = rotl32(x1, 16); x1 ^= x0;
  x0 += x1; x1 = rotl32(x1, 24); x1 ^= x0;
  x0 += k1; x1 += k2 + 4u;
  x0 += x1; x1 = rotl32(x1, 13); x1 ^= x0;
  x0 += x1; x1 = rotl32(x1, 15); x1 ^= x0;
  x0 += x1; x1 = rotl32(x1, 26); x1 ^= x0;
  x0 += x1; x1 = rotl32(x1, 6);  x1 ^= x0;
  x0 += k2; x1 += k0 + 5u;
  o0 = x0; o1 = x1;
}

// 23-bit uniform mantissa for flat index j under subkey (c0,c1).
__device__ __forceinline__ uint32_t rand_m23(uint32_t c0, uint32_t c1, uint32_t j) {
#if THREEFRY_PARTITIONABLE
  uint32_t o0, o1;
  threefry2x32(c0, c1, 0u, j, o0, o1);
  return (o0 ^ o1) >> 9;
#else
  uint32_t o0, o1;
  if (j < (uint32_t)HNK) {
    threefry2x32(c0, c1, j, j + (uint32_t)HNK, o0, o1);
    return o0 >> 9;
  }
  threefry2x32(c0, c1, j - (uint32_t)HNK, j, o0, o1);
  return o1 >> 9;
#endif
}

// ---------------------------------------------------------------------------
// Bit-exact IoU (no FMA contraction: equality/argmax vs numpy f32 sequence)
// ---------------------------------------------------------------------------
__device__ __forceinline__ float areaf(float x1, float y1, float x2, float y2) {
#pragma clang fp contract(off)
  return ((x2 - x1) + 1.0f) * ((y2 - y1) + 1.0f);
}

__device__ __forceinline__ float iou_f(float a0, float a1, float a2, float a3,
                                       float areaA, float g0, float g1, float g2,
                                       float g3, float areaG) {
#pragma clang fp contract(off)
  float ix1 = fmaxf(a0, g0);
  float iy1 = fmaxf(a1, g1);
  float ix2 = fminf(a2, g2);
  float iy2 = fminf(a3, g3);
  float iw = fmaxf((ix2 - ix1) + 1.0f, 0.0f);
  float ih = fmaxf((iy2 - iy1) + 1.0f, 0.0f);
  float inter = iw * ih;
  return inter / ((areaA + areaG) - inter);
}

// ---------------------------------------------------------------------------
// K0: zero colmax (1600 u32) + fgcnt (32 u32), contiguous at ws[0..1632)
// ---------------------------------------------------------------------------
__global__ __launch_bounds__(256) void k0_init(uint32_t* __restrict__ ws32) {
  int i = blockIdx.x * 256 + threadIdx.x;
  if (i < NI * MG + NI) ws32[i] = 0u;
}

// ---------------------------------------------------------------------------
// K1 v2: colmax[n][m] = max_k IoU(anchor k, gt (n,m)).
// m-chunked: block handles MCHUNK gt boxes (block-uniform -> SGPR-resident,
// zero LDS/VGPR cost), KC-way anchor split. best[MCHUNK] in VGPRs (~10),
// so occupancy is wave-cap-bound, not VGPR-bound; 10 independent IoUs per
// anchor give ILP to hide the f32-divide chains.
// ---------------------------------------------------------------------------
__global__ __launch_bounds__(256) void k1_colmax(const float4* __restrict__ a4,
                                                 const float* __restrict__ gt,
                                                 uint32_t* __restrict__ colmax) {
  int n = blockIdx.y;
  int m0 = blockIdx.z * MCHUNK;
  int tid = threadIdx.x;

  // block-uniform gt boxes + areas -> scalar loads / SGPRs
  float g[MCHUNK][4];
  float gA[MCHUNK];
  float best[MCHUNK];
#pragma unroll
  for (int i = 0; i < MCHUNK; ++i) {
    const float* p = gt + (n * MG + m0 + i) * 4;
    g[i][0] = p[0]; g[i][1] = p[1]; g[i][2] = p[2]; g[i][3] = p[3];
    gA[i] = areaf(g[i][0], g[i][1], g[i][2], g[i][3]);
    best[i] = 0.0f;
  }

  int per = (KA + KC - 1) / KC;           // 1407
  int kbeg = blockIdx.x * per;
  int kend = kbeg + per;
  if (kend > KA) kend = KA;
  for (int k = kbeg + tid; k < kend; k += 256) {
    float4 a = a4[k];
    float areaA = areaf(a.x, a.y, a.z, a.w);
#pragma unroll
    for (int i = 0; i < MCHUNK; ++i) {
      float v = iou_f(a.x, a.y, a.z, a.w, areaA,
                      g[i][0], g[i][1], g[i][2], g[i][3], gA[i]);
      best[i] = fmaxf(best[i], v);
    }
  }

#pragma unroll
  for (int i = 0; i < MCHUNK; ++i) {
    float b = best[i];
    b = fmaxf(b, __shfl_down(b, 32));
    b = fmaxf(b, __shfl_down(b, 16));
    b = fmaxf(b, __shfl_down(b, 8));
    b = fmaxf(b, __shfl_down(b, 4));
    b = fmaxf(b, __shfl_down(b, 2));
    b = fmaxf(b, __shfl_down(b, 1));
    if ((tid & 63) == 0)
      atomicMax(&colmax[n * MG + m0 + i], __float_as_uint(b));
  }
}

// ---------------------------------------------------------------------------
// K2: per-(n,k): flags, argmax gt, provisional f32 labels, f32 coeffs,
//     and per-row fg count (enables fg/bg phase parallelism in K3).
// ---------------------------------------------------------------------------
__global__ __launch_bounds__(256) void k2_main(const float4* __restrict__ a4,
                                               const float* __restrict__ gt,
                                               const uint32_t* __restrict__ colmax,
                                               float* __restrict__ out_lbl,
                                               float4* __restrict__ out_coeff,
                                               uint32_t* __restrict__ fgcnt) {
  int n = blockIdx.y;
  int tid = threadIdx.x;
  __shared__ float gs[MG * 4];
  __shared__ float gAs[MG];
  __shared__ uint32_t cms[MG];
  if (tid < MG * 4) gs[tid] = gt[n * MG * 4 + tid];
  __syncthreads();
  if (tid < MG) {
    gAs[tid] = areaf(gs[4 * tid], gs[4 * tid + 1], gs[4 * tid + 2], gs[4 * tid + 3]);
    cms[tid] = colmax[n * MG + tid];
  }
  __syncthreads();

  int k = blockIdx.x * 256 + tid;
  if (k >= KA) return;
  float4 a = a4[k];
  float areaA = areaf(a.x, a.y, a.z, a.w);

  float best = -1.0f;
  int bi = 0;
  bool anyp = false, anyn = false, abox = false;
#pragma unroll 5
  for (int m = 0; m < MG; ++m) {
    float v = iou_f(a.x, a.y, a.z, a.w, areaA,
                    gs[4 * m], gs[4 * m + 1], gs[4 * m + 2], gs[4 * m + 3], gAs[m]);
    if (v > best) { best = v; bi = m; }   // first-index argmax like np.argmax
    anyp = anyp || (v >= 0.7f);
    anyn = anyn || (v >= 0.3f);
    abox = abox || (__float_as_uint(v) == cms[m]);  // exact equality vs column max
  }
  bool is_fg = abox || anyp;
  out_lbl[n * KA + k] = is_fg ? 1.0f : (anyn ? -1.0f : 0.0f);
  if (is_fg) atomicAdd(&fgcnt[n], 1u);

  // regression coefficients to argmax gt box (own block so the pragma is legal)
  {
#pragma clang fp contract(off)
    float g0 = gs[4 * bi], g1 = gs[4 * bi + 1], g2 = gs[4 * bi + 2], g3 = gs[4 * bi + 3];
    float aw = a.z - a.x + 1.0f, ah = a.w - a.y + 1.0f;
    float ax = a.x + 0.5f * aw, ay = a.y + 0.5f * ah;
    float gw = g2 - g0 + 1.0f, gh = g3 - g1 + 1.0f;
    float gx = g0 + 0.5f * gw, gy = g1 + 0.5f * gh;
    float4 c;
    c.x = (gx - ax) / aw;
    c.y = (gy - ay) / ah;
    c.z = logf(gw / aw);
    c.w = logf(gh / ah);
    out_coeff[n * KA + k] = c;
  }
}

// ---------------------------------------------------------------------------
// K3: fully parallel T-th order statistic per (row, phase).
// Grid (NI, 2): blockIdx.y = 0 -> fg (T=128), 1 -> bg (T=256-min(fg,128)).
// ---------------------------------------------------------------------------
__global__ __launch_bounds__(256) void k3_select(const float* __restrict__ lbl,
                                                 const uint32_t* __restrict__ fgcnt,
                                                 uint64_t* __restrict__ theta_fg,
                                                 uint64_t* __restrict__ theta_bg,
                                                 uint32_t k10, uint32_t k11,
                                                 uint32_t k20, uint32_t k21) {
  __shared__ uint32_t hist[NBUCK];     // 16 KB
  __shared__ uint32_t mcache[KA];      // 90 KB (sentinel 0xFFFFFFFF = non-match)
  __shared__ uint32_t colm[SELCAP];
  __shared__ uint32_t colk[SELCAP];
  __shared__ uint32_t wtot[4];
  __shared__ uint32_t ccnt;
  __shared__ int sB;
  __shared__ uint32_t sR;

  int n = blockIdx.x;
  int phase = blockIdx.y;
  int tid = threadIdx.x;
  int lane = tid & 63;
  int wv = tid >> 6;
  const float* lb = lbl + n * KA;

  float match = phase ? 0.0f : 1.0f;
  uint32_t c0 = phase ? k20 : k10;
  uint32_t c1 = phase ? k21 : k11;
  uint64_t* theta = phase ? theta_bg : theta_fg;

  for (int i = tid; i < NBUCK; i += 256) hist[i] = 0u;
  if (tid == 0) { ccnt = 0u; sB = -1; }
  __syncthreads();

  // 1. histogram + m23 cache
  for (int k = tid; k < KA; k += 256) {
    uint32_t m = 0xFFFFFFFFu;
    if (lb[k] == match) {
      m = rand_m23(c0, c1, (uint32_t)(n * KA + k));
      atomicAdd(&hist[m >> 11], 1u);
    }
    mcache[k] = m;
  }
  __syncthreads();

  // 2. block scan over 16-bucket chunks
  const int CPB = NBUCK / 256;  // 16 buckets per thread
  int base = tid * CPB;
  uint32_t csum = 0;
#pragma unroll
  for (int i = 0; i < CPB; ++i) csum += hist[base + i];
  uint32_t x = csum;
#pragma unroll
  for (int d = 1; d < 64; d <<= 1) {
    uint32_t y = __shfl_up(x, d, 64);
    if (lane >= d) x += y;
  }
  if (lane == 63) wtot[wv] = x;
  __syncthreads();
  uint32_t woff = 0;
  for (int w = 0; w < wv; ++w) woff += wtot[w];
  uint32_t incl = x + woff;            // inclusive prefix over chunk sums
  uint32_t excl = incl - csum;
  uint32_t total = wtot[0] + wtot[1] + wtot[2] + wtot[3];

  uint32_t nf = fgcnt[n];
  uint32_t numfg = nf < (uint32_t)MAXFG ? nf : (uint32_t)MAXFG;
  uint32_t T = phase == 0 ? (uint32_t)MAXFG : (uint32_t)TOTALA - numfg;

  if (total <= T) {
    if (tid == 0) theta[n] = ~0ull;    // keep all matching
    return;
  }

  // crossing chunk: unique thread with excl < T <= incl
  if (excl < T && T <= incl) {
    uint32_t cum = excl;
    for (int i = 0; i < CPB; ++i) {
      uint32_t h = hist[base + i];
      if (cum + h >= T) { sB = base + i; sR = T - cum; break; }
      cum += h;
    }
  }
  __syncthreads();

  // 3. collect candidates in the crossing bucket (from cache; no threefry)
  int b = sB;
  for (int k = tid; k < KA; k += 256) {
    uint32_t m = mcache[k];
    if ((int)(m >> 11) == b) {
      uint32_t i = atomicAdd(&ccnt, 1u);
      if (i < SELCAP) { colm[i] = m; colk[i] = (uint32_t)k; }
    }
  }
  __syncthreads();

  // 4. parallel rank selection: the sR-th smallest key (keys distinct)
  uint32_t C = ccnt < (uint32_t)SELCAP ? ccnt : (uint32_t)SELCAP;
  uint32_t r = sR;
  for (uint32_t c = tid; c < C; c += 256) {
    uint64_t key = ((uint64_t)colm[c] << 32) | (uint64_t)colk[c];
    uint32_t less = 0;
    for (uint32_t j = 0; j < C; ++j) {
      uint64_t kj = ((uint64_t)colm[j] << 32) | (uint64_t)colk[j];
      less += (kj < key) ? 1u : 0u;
    }
    if (less == r - 1u) theta[n] = key;
  }
}

// ---------------------------------------------------------------------------
// K4: final labels (drop fg/bg beyond threshold) + anchors_idx (f32)
// ---------------------------------------------------------------------------
__global__ __launch_bounds__(256) void k4_final(float* __restrict__ lbl,
                                                float* __restrict__ out_idx,
                                                const uint64_t* __restrict__ theta_fg,
                                                const uint64_t* __restrict__ theta_bg,
                                                uint32_t k10, uint32_t k11,
                                                uint32_t k20, uint32_t k21) {
  int n = blockIdx.y;
  int k = blockIdx.x * 256 + threadIdx.x;
  if (k >= KA) return;
  float v = lbl[n * KA + k];
  if (v == 1.0f) {
    uint64_t key = ((uint64_t)rand_m23(k10, k11, (uint32_t)(n * KA + k)) << 32) | (uint32_t)k;
    if (key > theta_fg[n]) lbl[n * KA + k] = -1.0f;
  } else if (v == 0.0f) {
    uint64_t key = ((uint64_t)rand_m23(k20, k21, (uint32_t)(n * KA + k)) << 32) | (uint32_t)k;
    if (key > theta_bg[n]) lbl[n * KA + k] = -1.0f;
  }
  if (n == 0) out_idx[k] = (float)k;  // all anchors kept by construction
}

// ---------------------------------------------------------------------------
// Launch
// ---------------------------------------------------------------------------
extern "C" void kernel_launch(void* const* d_in, const int* in_sizes, int n_in,
                              void* d_out, int out_size, void* d_ws, size_t ws_size,
                              hipStream_t stream) {
  const float* anchors = (const float*)d_in[0];   // [22500,4] f32
  const float* gt = (const float*)d_in[1];        // [32,50,4] f32
  float* out_f = (float*)d_out;                   // f32 buffer, 3,622,500 elems
  float* out_lbl = out_f;                         // [32,22500]
  float4* out_coeff = (float4*)(out_f + COEFF_OFF);  // [32,22500,4], 16B-aligned
  float* out_idx = out_f + IDX_OFF;               // [22500]

  // ws layout (u32): colmax [0,1600) | fgcnt [1600,1632) | theta_fg @byte 6528 | theta_bg @6784
  uint32_t* ws32 = (uint32_t*)d_ws;
  uint32_t* colmax = ws32;
  uint32_t* fgcnt = ws32 + NI * MG;
  uint64_t* theta_fg = (uint64_t*)((char*)d_ws + 6528);
  uint64_t* theta_bg = (uint64_t*)((char*)d_ws + 6784);

  // subkeys of jax.random.split(jax.random.key(42)), derived host-side
  uint32_t k10, k11, k20, k21;
#if THREEFRY_PARTITIONABLE
  threefry2x32(0u, 42u, 0u, 0u, k10, k11);
  threefry2x32(0u, 42u, 0u, 1u, k20, k21);
#else
  uint32_t a0, a1, b0, b1;
  threefry2x32(0u, 42u, 0u, 2u, a0, a1);
  threefry2x32(0u, 42u, 1u, 3u, b0, b1);
  k10 = a0; k11 = b0;
  k20 = a1; k21 = b1;
#endif

  const int KBLK = (KA + 255) / 256;  // 88
  k0_init<<<7, 256, 0, stream>>>(ws32);
  k1_colmax<<<dim3(KC, NI, MG / MCHUNK), 256, 0, stream>>>((const float4*)anchors,
                                                           gt, colmax);
  k2_main<<<dim3(KBLK, NI), 256, 0, stream>>>((const float4*)anchors, gt, colmax,
                                              out_lbl, out_coeff, fgcnt);
  k3_select<<<dim3(NI, 2), 256, 0, stream>>>(out_lbl, fgcnt, theta_fg, theta_bg,
                                             k10, k11, k20, k21);
  k4_final<<<dim3(KBLK, NI), 256, 0, stream>>>(out_lbl, out_idx, theta_fg, theta_bg,
                                               k10, k11, k20, k21);
}